// Round 2
// baseline (1873.412 us; speedup 1.0000x reference)
//
#include <hip/hip_runtime.h>
#include <math.h>

// Problem constants (fixed by setup_inputs)
static constexpr int BATCH = 32;
static constexpr int NPRED = 512;   // outputs rows (LAP columns)
static constexpr int NTGT  = 200;   // targets rows (LAP rows)
static constexpr int DIM   = 768;
#define BIGF 1e9f

// ---------------------------------------------------------------------------
// Row squared-norms: one wave per row, 768 floats = 192 float4 = 64 lanes x 3
// ---------------------------------------------------------------------------
__global__ __launch_bounds__(64) void row_norms_kernel(const float* __restrict__ x,
                                                       float* __restrict__ out) {
    int row = blockIdx.x;
    const float4* r = (const float4*)(x + (size_t)row * DIM);
    float s = 0.f;
#pragma unroll
    for (int k = 0; k < 3; ++k) {
        float4 v = r[threadIdx.x + 64 * k];
        s += v.x * v.x + v.y * v.y + v.z * v.z + v.w * v.w;
    }
#pragma unroll
    for (int off = 32; off; off >>= 1) s += __shfl_down(s, off);
    if (threadIdx.x == 0) out[row] = s;
}

// ---------------------------------------------------------------------------
// cost[b][m][n] = sqrt(max(nt[m] + no[n] - 2 * dot(T[m], O[n]), 0))
// Tiled fp32 GEMM: 32(m) x 128(n) tile, BK=32, 256 threads, 4x4 acc/thread.
// ---------------------------------------------------------------------------
__global__ __launch_bounds__(256) void cost_kernel(const float* __restrict__ O,
                                                   const float* __restrict__ T,
                                                   const float* __restrict__ no_arr,
                                                   const float* __restrict__ nt_arr,
                                                   float* __restrict__ cost) {
    const int b  = blockIdx.z;
    const int m0 = blockIdx.y * 32;
    const int n0 = blockIdx.x * 128;
    const float* Tb = T + (size_t)b * NTGT * DIM;
    const float* Ob = O + (size_t)b * NPRED * DIM;

    __shared__ float As[32][33];   // [k][m], +1 pad
    __shared__ float Bs[32][129];  // [k][n], +1 pad

    const int tid = threadIdx.x;
    const int tx = tid & 31;   // n
    const int ty = tid >> 5;   // m

    float acc[4][4] = {};

    for (int k0 = 0; k0 < DIM; k0 += 32) {
        // A tile: 32 rows x 32 k = 256 float4, one per thread (clamped rows)
        {
            int ar = tid >> 3;
            int ak = (tid & 7) << 2;
            int gm = m0 + ar; if (gm > NTGT - 1) gm = NTGT - 1;
            float4 vA = *(const float4*)(Tb + (size_t)gm * DIM + k0 + ak);
            As[ak + 0][ar] = vA.x; As[ak + 1][ar] = vA.y;
            As[ak + 2][ar] = vA.z; As[ak + 3][ar] = vA.w;
        }
        // B tile: 128 rows x 32 k = 1024 float4, four per thread
#pragma unroll
        for (int q = 0; q < 4; ++q) {
            int idx = q * 256 + tid;
            int br = idx >> 3;
            int bk = (idx & 7) << 2;
            float4 vB = *(const float4*)(Ob + (size_t)(n0 + br) * DIM + k0 + bk);
            Bs[bk + 0][br] = vB.x; Bs[bk + 1][br] = vB.y;
            Bs[bk + 2][br] = vB.z; Bs[bk + 3][br] = vB.w;
        }
        __syncthreads();
#pragma unroll
        for (int k = 0; k < 32; ++k) {
            float a0 = As[k][ty], a1 = As[k][ty + 8],
                  a2 = As[k][ty + 16], a3 = As[k][ty + 24];
            float b0 = Bs[k][tx],      b1 = Bs[k][tx + 32],
                  b2 = Bs[k][tx + 64], b3 = Bs[k][tx + 96];
            acc[0][0] += a0 * b0; acc[0][1] += a0 * b1; acc[0][2] += a0 * b2; acc[0][3] += a0 * b3;
            acc[1][0] += a1 * b0; acc[1][1] += a1 * b1; acc[1][2] += a1 * b2; acc[1][3] += a1 * b3;
            acc[2][0] += a2 * b0; acc[2][1] += a2 * b1; acc[2][2] += a2 * b2; acc[2][3] += a2 * b3;
            acc[3][0] += a3 * b0; acc[3][1] += a3 * b1; acc[3][2] += a3 * b2; acc[3][3] += a3 * b3;
        }
        __syncthreads();
    }

#pragma unroll
    for (int i = 0; i < 4; ++i) {
        int gm = m0 + ty + 8 * i;
        if (gm < NTGT) {
            float ntv = nt_arr[b * NTGT + gm];
#pragma unroll
            for (int j = 0; j < 4; ++j) {
                int gn = n0 + tx + 32 * j;
                float d2 = ntv + no_arr[b * NPRED + gn] - 2.0f * acc[i][j];
                cost[((size_t)b * NTGT + gm) * NPRED + gn] = sqrtf(fmaxf(d2, 0.0f));
            }
        }
    }
}

// ---------------------------------------------------------------------------
// Jonker-Volgenant LAP, ONE WAVE (64 threads) per batch; lane owns 8 columns
// (col = q*64 + lane + 1). Per-column duals v / minv / used in registers;
// u / p / way in LDS. Single-wave blocks: s_barrier is immediate, only the
// lgkmcnt drain matters. Argmin = 6-step __shfl_xor butterfly with
// first-index tie-break (matches jnp.argmin). Arithmetic order identical to
// the round-1 kernel (verified absmax 0 vs reference).
// ---------------------------------------------------------------------------
__global__ __launch_bounds__(64) void lap_kernel(const float* __restrict__ cost,
                                                 int* __restrict__ out) {
    const int b = blockIdx.x;
    const int lane = threadIdx.x;
    const float* C = cost + (size_t)b * NTGT * NPRED;  // [NTGT][NPRED]

    __shared__ float u_lds[NTGT + 1];
    __shared__ int   p_lds[NPRED + 1];
    __shared__ int   way_lds[NPRED];  // indexed by col-1
    __shared__ int   g2p[NTGT];

    for (int k = lane; k < NTGT + 1; k += 64) u_lds[k] = 0.f;
    for (int k = lane; k < NPRED + 1; k += 64) p_lds[k] = 0;
    float v[8], minv[8];
    int used[8];
#pragma unroll
    for (int q = 0; q < 8; ++q) v[q] = 0.f;
    __syncthreads();

    for (int i = 1; i <= NTGT; ++i) {
        if (lane == 0) p_lds[0] = i;
        float pre[8];
#pragma unroll
        for (int q = 0; q < 8; ++q) {
            minv[q] = BIGF;
            used[q] = 0;
            way_lds[q * 64 + lane] = 0;
            pre[q] = C[(size_t)(i - 1) * NPRED + q * 64 + lane];  // prefetch row i
        }
        __syncthreads();

        int j0 = 0;
        int j1 = 0;
        bool first = true;
        for (int it = 0; it < NPRED + 1; ++it) {
            int i0 = p_lds[j0];           // uniform (broadcast LDS read)
            float u_i0 = u_lds[i0];
#pragma unroll
            for (int q = 0; q < 8; ++q) {
                int col1 = q * 64 + lane + 1;
                if (col1 == j0) used[q] = 1;  // mark current col used
                if (!used[q]) {
                    float cv = first ? pre[q]
                                     : C[(size_t)(i0 - 1) * NPRED + (col1 - 1)];
                    float cur = cv - u_i0 - v[q];
                    if (cur < minv[q]) { minv[q] = cur; way_lds[col1 - 1] = j0; }
                }
            }
            first = false;

            // argmin over masked = used ? BIG : minv, first-index tie-break
            float bv = BIGF;
            int bi = NPRED + 1;
#pragma unroll
            for (int q = 0; q < 8; ++q) {
                float m = used[q] ? BIGF : minv[q];
                int c = q * 64 + lane + 1;
                if (m < bv || (m == bv && c < bi)) { bv = m; bi = c; }
            }
#pragma unroll
            for (int off = 1; off < 64; off <<= 1) {
                float ov = __shfl_xor(bv, off);
                int   oi = __shfl_xor(bi, off);
                if (ov < bv || (ov == bv && oi < bi)) { bv = ov; bi = oi; }
            }
            float delta = bv;
            j1 = bi;
            int done = (p_lds[j1] == 0);

            // dual updates (same op order as reference)
#pragma unroll
            for (int q = 0; q < 8; ++q) {
                if (used[q]) {
                    v[q] -= delta;
                    int pr = p_lds[q * 64 + lane + 1];
                    u_lds[pr] += delta;  // distinct rows per used col: race-free
                } else {
                    minv[q] -= delta;
                }
            }
            if (lane == 0) u_lds[p_lds[0]] += delta;  // virtual col 0 -> row i
            __syncthreads();
            if (done) break;
            j0 = j1;
        }

        // backtrack augmenting path (sequential, short)
        if (lane == 0) {
            int j = j1;
            while (j != 0) {
                int w = way_lds[j - 1];
                p_lds[j] = p_lds[w];
                j = w;
            }
        }
        __syncthreads();  // order backtrack writes vs next row's way reset / p reads
    }

    // invert matching: g2p[row] = col (0-based pred index)
    for (int col = lane; col < NPRED; col += 64) {
        int r = p_lds[col + 1];
        if (r > 0) g2p[r - 1] = col;
    }
    __syncthreads();

    // sort by pred index via rank counting (values distinct)
    for (int t = lane; t < NTGT; t += 64) {
        int myv = g2p[t];
        int rank = 0;
        for (int l = 0; l < NTGT; ++l) rank += (g2p[l] < myv) ? 1 : 0;
        out[b * 2 * NTGT + rank] = myv;          // index_i: sorted pred indices
        out[b * 2 * NTGT + NTGT + rank] = t;     // index_j: gt index (argsort)
    }
}

extern "C" void kernel_launch(void* const* d_in, const int* in_sizes, int n_in,
                              void* d_out, int out_size, void* d_ws, size_t ws_size,
                              hipStream_t stream) {
    const float* outputs = (const float*)d_in[0];  // [32, 512, 768]
    const float* targets = (const float*)d_in[1];  // [32, 200, 768]
    int* out = (int*)d_out;                        // [32, 2, 200] int32

    float* cost   = (float*)d_ws;                         // [32][200][512]
    float* no_arr = cost + (size_t)BATCH * NTGT * NPRED;  // [32*512]
    float* nt_arr = no_arr + (size_t)BATCH * NPRED;       // [32*200]

    row_norms_kernel<<<BATCH * NPRED, 64, 0, stream>>>(outputs, no_arr);
    row_norms_kernel<<<BATCH * NTGT, 64, 0, stream>>>(targets, nt_arr);
    cost_kernel<<<dim3(NPRED / 128, (NTGT + 31) / 32, BATCH), 256, 0, stream>>>(
        outputs, targets, no_arr, nt_arr, cost);
    lap_kernel<<<BATCH, 64, 0, stream>>>(cost, out);
}

// Round 3
// 877.077 us; speedup vs baseline: 2.1360x; 2.1360x over previous
//
#include <hip/hip_runtime.h>
#include <math.h>

// Problem constants (fixed by setup_inputs)
static constexpr int BATCH = 32;
static constexpr int NPRED = 512;   // outputs rows (LAP columns)
static constexpr int NTGT  = 200;   // targets rows (LAP rows)
static constexpr int DIM   = 768;
#define BIGF  1e9f                  // fresh-minv init (matches reference BIG)
#define USEDC 2e9f                  // sentinel: column is 'used'

// ---------------------------------------------------------------------------
// Row squared-norms: one wave per row
// ---------------------------------------------------------------------------
__global__ __launch_bounds__(64) void row_norms_kernel(const float* __restrict__ x,
                                                       float* __restrict__ out) {
    int row = blockIdx.x;
    const float4* r = (const float4*)(x + (size_t)row * DIM);
    float s = 0.f;
#pragma unroll
    for (int k = 0; k < 3; ++k) {
        float4 v = r[threadIdx.x + 64 * k];
        s += v.x * v.x + v.y * v.y + v.z * v.z + v.w * v.w;
    }
#pragma unroll
    for (int off = 32; off; off >>= 1) s += __shfl_down(s, off);
    if (threadIdx.x == 0) out[row] = s;
}

// ---------------------------------------------------------------------------
// cost[b][m][n] = sqrt(max(nt[m] + no[n] - 2 * dot(T[m], O[n]), 0))
// Tiled fp32 GEMM: 32(m) x 128(n) tile, BK=32, 256 threads, 4x4 acc/thread.
// ---------------------------------------------------------------------------
__global__ __launch_bounds__(256) void cost_kernel(const float* __restrict__ O,
                                                   const float* __restrict__ T,
                                                   const float* __restrict__ no_arr,
                                                   const float* __restrict__ nt_arr,
                                                   float* __restrict__ cost) {
    const int b  = blockIdx.z;
    const int m0 = blockIdx.y * 32;
    const int n0 = blockIdx.x * 128;
    const float* Tb = T + (size_t)b * NTGT * DIM;
    const float* Ob = O + (size_t)b * NPRED * DIM;

    __shared__ float As[32][33];   // [k][m], +1 pad
    __shared__ float Bs[32][129];  // [k][n], +1 pad

    const int tid = threadIdx.x;
    const int tx = tid & 31;   // n
    const int ty = tid >> 5;   // m

    float acc[4][4] = {};

    for (int k0 = 0; k0 < DIM; k0 += 32) {
        {
            int ar = tid >> 3;
            int ak = (tid & 7) << 2;
            int gm = m0 + ar; if (gm > NTGT - 1) gm = NTGT - 1;
            float4 vA = *(const float4*)(Tb + (size_t)gm * DIM + k0 + ak);
            As[ak + 0][ar] = vA.x; As[ak + 1][ar] = vA.y;
            As[ak + 2][ar] = vA.z; As[ak + 3][ar] = vA.w;
        }
#pragma unroll
        for (int q = 0; q < 4; ++q) {
            int idx = q * 256 + tid;
            int br = idx >> 3;
            int bk = (idx & 7) << 2;
            float4 vB = *(const float4*)(Ob + (size_t)(n0 + br) * DIM + k0 + bk);
            Bs[bk + 0][br] = vB.x; Bs[bk + 1][br] = vB.y;
            Bs[bk + 2][br] = vB.z; Bs[bk + 3][br] = vB.w;
        }
        __syncthreads();
#pragma unroll
        for (int k = 0; k < 32; ++k) {
            float a0 = As[k][ty], a1 = As[k][ty + 8],
                  a2 = As[k][ty + 16], a3 = As[k][ty + 24];
            float b0 = Bs[k][tx],      b1 = Bs[k][tx + 32],
                  b2 = Bs[k][tx + 64], b3 = Bs[k][tx + 96];
            acc[0][0] += a0 * b0; acc[0][1] += a0 * b1; acc[0][2] += a0 * b2; acc[0][3] += a0 * b3;
            acc[1][0] += a1 * b0; acc[1][1] += a1 * b1; acc[1][2] += a1 * b2; acc[1][3] += a1 * b3;
            acc[2][0] += a2 * b0; acc[2][1] += a2 * b1; acc[2][2] += a2 * b2; acc[2][3] += a2 * b3;
            acc[3][0] += a3 * b0; acc[3][1] += a3 * b1; acc[3][2] += a3 * b2; acc[3][3] += a3 * b3;
        }
        __syncthreads();
    }

#pragma unroll
    for (int i = 0; i < 4; ++i) {
        int gm = m0 + ty + 8 * i;
        if (gm < NTGT) {
            float ntv = nt_arr[b * NTGT + gm];
#pragma unroll
            for (int j = 0; j < 4; ++j) {
                int gn = n0 + tx + 32 * j;
                float d2 = ntv + no_arr[b * NPRED + gn] - 2.0f * acc[i][j];
                cost[((size_t)b * NTGT + gm) * NPRED + gn] = sqrtf(fmaxf(d2, 0.0f));
            }
        }
    }
}

// ---------------------------------------------------------------------------
// LAP helpers
// ---------------------------------------------------------------------------
__device__ __forceinline__ int rl(int v, int l) {
    return __builtin_amdgcn_readlane(v, l);
}
__device__ __forceinline__ float rlf(float v, int l) {
    return __int_as_float(__builtin_amdgcn_readlane(__float_as_int(v), l));
}
__device__ __forceinline__ int sel8i(const int* a, int s) {
    int r = a[0];
#pragma unroll
    for (int k = 1; k < 8; ++k) r = (s == k) ? a[k] : r;
    return r;
}
__device__ __forceinline__ float sel8f(const float* a, int s) {
    float r = a[0];
#pragma unroll
    for (int k = 1; k < 8; ++k) r = (s == k) ? a[k] : r;
    return r;
}
// Wave-wide min via DPP (VALU-only): lane 63 ends with min of all 64 lanes.
__device__ __forceinline__ float dpp_min_f32(float x) {
    float t;
    t = __int_as_float(__builtin_amdgcn_update_dpp(__float_as_int(x), __float_as_int(x), 0x111, 0xF, 0xF, false)); x = fminf(x, t);
    t = __int_as_float(__builtin_amdgcn_update_dpp(__float_as_int(x), __float_as_int(x), 0x112, 0xF, 0xF, false)); x = fminf(x, t);
    t = __int_as_float(__builtin_amdgcn_update_dpp(__float_as_int(x), __float_as_int(x), 0x114, 0xF, 0xF, false)); x = fminf(x, t);
    t = __int_as_float(__builtin_amdgcn_update_dpp(__float_as_int(x), __float_as_int(x), 0x118, 0xF, 0xF, false)); x = fminf(x, t);
    t = __int_as_float(__builtin_amdgcn_update_dpp(__float_as_int(x), __float_as_int(x), 0x142, 0xF, 0xF, false)); x = fminf(x, t);
    t = __int_as_float(__builtin_amdgcn_update_dpp(__float_as_int(x), __float_as_int(x), 0x143, 0xF, 0xF, false)); x = fminf(x, t);
    return x;
}

// ---------------------------------------------------------------------------
// Jonker-Volgenant LAP, ONE WAVE per batch, ZERO barriers / LDS reads inside
// the Dijkstra iteration. Lane-major columns: col(0-based) = lane*8 + q.
// All per-column state (v, minv, up=u0[p[col]], p, way) in registers.
// used <=> minv == USEDC sentinel. Argmin: lane-local tree (tie: lower q)
// -> DPP fminf reduce -> ballot+ctz (tie: lower lane = lower col, matching
// jnp.argmin first-index). Float op order identical to reference (bit-exact).
// ---------------------------------------------------------------------------
__global__ __launch_bounds__(64) void lap_kernel(const float* __restrict__ cost,
                                                 int* __restrict__ out) {
    const int b = blockIdx.x;
    const int lane = threadIdx.x;
    const float* C = cost + (size_t)b * NTGT * NPRED;
    const float* Cl = C + lane * 8;   // lane's 8-column slice base

    __shared__ float u0[NTGT + 1];    // row duals (stable during a row-step)
    __shared__ int g2p[NTGT];

    for (int k = lane; k < NTGT + 1; k += 64) u0[k] = 0.f;

    float v[8], minv[8], up[8];
    int p_arr[8], way_arr[8];
#pragma unroll
    for (int q = 0; q < 8; ++q) {
        v[q] = 0.f; up[q] = 0.f; p_arr[q] = 0; way_arr[q] = 0;
    }
    __syncthreads();

    // prefetch row 0 (first scan of row-step i=1)
    float4 ca = *(const float4*)(Cl);
    float4 cb = *(const float4*)(Cl + 4);

    for (int i = 1; i <= NTGT; ++i) {
#pragma unroll
        for (int q = 0; q < 8; ++q) minv[q] = BIGF;
        float uI = 0.f;       // u[i] accumulator (virtual col 0), uniform
        float u_i0 = 0.f;     // u0 of current scan row (row i starts at 0)
        int j0 = 0;
        int j1 = 0;

        for (int it = 0; it <= NPRED; ++it) {
            float c[8];
            c[0] = ca.x; c[1] = ca.y; c[2] = ca.z; c[3] = ca.w;
            c[4] = cb.x; c[5] = cb.y; c[6] = cb.z; c[7] = cb.w;

            // scan row i0: reduced cost, same float order as reference
#pragma unroll
            for (int q = 0; q < 8; ++q) {
                float cur = (c[q] - u_i0) - v[q];
                bool usedq = (minv[q] == USEDC);
                float cure = usedq ? USEDC : cur;   // used cols never improve
                bool imp = cure < minv[q];
                minv[q] = imp ? cure : minv[q];
                way_arr[q] = imp ? j0 : way_arr[q];
            }

            // lane-local argmin tree over 8 cols (tie -> lower q)
            float v01 = (minv[0] <= minv[1]) ? minv[0] : minv[1];
            int   q01 = (minv[0] <= minv[1]) ? 0 : 1;
            float v23 = (minv[2] <= minv[3]) ? minv[2] : minv[3];
            int   q23 = (minv[2] <= minv[3]) ? 2 : 3;
            float v45 = (minv[4] <= minv[5]) ? minv[4] : minv[5];
            int   q45 = (minv[4] <= minv[5]) ? 4 : 5;
            float v67 = (minv[6] <= minv[7]) ? minv[6] : minv[7];
            int   q67 = (minv[6] <= minv[7]) ? 6 : 7;
            float v03 = (v01 <= v23) ? v01 : v23;
            int   q03 = (v01 <= v23) ? q01 : q23;
            float v47 = (v45 <= v67) ? v45 : v67;
            int   q47 = (v45 <= v67) ? q45 : q67;
            float lval = (v03 <= v47) ? v03 : v47;
            int   lq   = (v03 <= v47) ? q03 : q47;

            // winner's payload pre-selected per-lane (hidden under DPP)
            int   psel = sel8i(p_arr, lq);
            float usel = sel8f(up, lq);

            // wave argmin
            float wmin = dpp_min_f32(lval);
            wmin = rlf(wmin, 63);                       // uniform min value
            unsigned long long mask = __ballot(lval == wmin);
            int w = (int)__builtin_ctzll(mask);         // lowest lane = lowest col
            int qw = rl(lq, w);
            int i0n = rl(psel, w);                      // p[j1]
            float u_n = rlf(usel, w);                   // u0[p[j1]]
            float delta = wmin;
            j1 = w * 8 + qw + 1;
            bool done = (i0n == 0);

            // issue next row's loads ASAP (latency hides the updates below)
            if (!done) {
                const float* Crow = Cl + (size_t)(i0n - 1) * NPRED;
                ca = *(const float4*)(Crow);
                cb = *(const float4*)(Crow + 4);
            }

            // dual updates (reference order; j1 not yet marked used)
            uI += delta;
#pragma unroll
            for (int q = 0; q < 8; ++q) {
                bool usedq = (minv[q] == USEDC);
                v[q]    = usedq ? (v[q] - delta) : v[q];
                up[q]   = usedq ? (up[q] + delta) : up[q];
                minv[q] = usedq ? minv[q] : (minv[q] - delta);
            }
            // mark j1 used
            int j1m1 = j1 - 1;
#pragma unroll
            for (int q = 0; q < 8; ++q) {
                bool mine = (lane * 8 + q) == j1m1;
                minv[q] = mine ? USEDC : minv[q];
            }

            if (done) break;
            u_i0 = u_n;
            j0 = j1;
        }

        // prefetch next row-step's first scan row (independent of backtrack)
        if (i < NTGT) {
            const float* Crow = Cl + (size_t)i * NPRED;
            ca = *(const float4*)(Crow);
            cb = *(const float4*)(Crow + 4);
        }

        // write back u (pre-augment p): used cols carry u0[p]+deltas in up[]
#pragma unroll
        for (int q = 0; q < 8; ++q) {
            bool usedq = (minv[q] == USEDC);
            if (usedq && p_arr[q] != 0) u0[p_arr[q]] = up[q];
        }
        if (lane == 0) u0[i] = uI;

        // backtrack augmenting path (uniform scalar walk over registers)
        {
            int j = j1;
            for (int s = 0; s <= NPRED; ++s) {
                int ow = (j - 1) >> 3, oq = (j - 1) & 7;
                int wj = rl(sel8i(way_arr, oq), ow);    // way[j]
                int pOfW;
                if (wj == 0) {
                    pOfW = i;                           // p[0] = i (virtual)
                } else {
                    int ow2 = (wj - 1) >> 3, oq2 = (wj - 1) & 7;
                    pOfW = rl(sel8i(p_arr, oq2), ow2);  // old p[way[j]]
                }
#pragma unroll
                for (int q = 0; q < 8; ++q) {
                    bool mine = (lane == ow) && (q == oq);
                    p_arr[q] = mine ? pOfW : p_arr[q];
                }
                if (wj == 0) break;
                j = wj;
            }
        }

        __syncthreads();  // u0 write-back visible before refresh reads
        // refresh up = u0[p[col]] with post-augment p
#pragma unroll
        for (int q = 0; q < 8; ++q) up[q] = u0[p_arr[q]];
    }

    // invert matching: g2p[row] = col (0-based pred index)
#pragma unroll
    for (int q = 0; q < 8; ++q) {
        int r = p_arr[q];
        if (r > 0) g2p[r - 1] = lane * 8 + q;
    }
    __syncthreads();

    // sort by pred index via rank counting (values distinct)
    for (int t = lane; t < NTGT; t += 64) {
        int myv = g2p[t];
        int rank = 0;
        for (int l = 0; l < NTGT; ++l) rank += (g2p[l] < myv) ? 1 : 0;
        out[b * 2 * NTGT + rank] = myv;          // index_i: sorted pred indices
        out[b * 2 * NTGT + NTGT + rank] = t;     // index_j: gt index (argsort)
    }
}

extern "C" void kernel_launch(void* const* d_in, const int* in_sizes, int n_in,
                              void* d_out, int out_size, void* d_ws, size_t ws_size,
                              hipStream_t stream) {
    const float* outputs = (const float*)d_in[0];  // [32, 512, 768]
    const float* targets = (const float*)d_in[1];  // [32, 200, 768]
    int* out = (int*)d_out;                        // [32, 2, 200] int32

    float* cost   = (float*)d_ws;                         // [32][200][512]
    float* no_arr = cost + (size_t)BATCH * NTGT * NPRED;  // [32*512]
    float* nt_arr = no_arr + (size_t)BATCH * NPRED;       // [32*200]

    row_norms_kernel<<<BATCH * NPRED, 64, 0, stream>>>(outputs, no_arr);
    row_norms_kernel<<<BATCH * NTGT, 64, 0, stream>>>(targets, nt_arr);
    cost_kernel<<<dim3(NPRED / 128, (NTGT + 31) / 32, BATCH), 256, 0, stream>>>(
        outputs, targets, no_arr, nt_arr, cost);
    lap_kernel<<<BATCH, 64, 0, stream>>>(cost, out);
}